// Round 3
// baseline (208.082 us; speedup 1.0000x reference)
//
#include <hip/hip_runtime.h>

#define IN_H 200
#define IN_W 200
#define NCH  256
#define NROI 512
#define OUT_HW 49
#define PLANE (IN_H * IN_W)
#define MAXR 48           // max region side: 6.5*max_bin(6.857)+2 < 48
#define REGSZ (MAXR * MAXR)

__global__ __launch_bounds__(256) void roi_align_kernel(
    const float* __restrict__ input,
    const float* __restrict__ rois,
    float* __restrict__ out) {
  __shared__ float sreg[4][REGSZ];   // 36864 B: one 48x48 region per wave

  const int blk  = blockIdx.x;
  const int k    = blk >> 6;          // roi index
  const int cg   = blk & 63;          // channel group (4 channels)
  const int wave = threadIdx.x >> 6;  // 0..3
  const int lane = threadIdx.x & 63;
  const int c    = (cg << 2) + wave;

  const float* r = rois + k * 5;
  const int   b   = (int)r[0];
  const float x1s = r[1] * 0.25f;
  const float y1s = r[2] * 0.25f;
  const float x2s = r[3] * 0.25f;
  const float y2s = r[4] * 0.25f;
  const float roi_w = fmaxf(x2s - x1s, 1.0f);
  const float roi_h = fmaxf(y2s - y1s, 1.0f);
  const float bw = roi_w / 7.0f;
  const float bh = roi_h / 7.0f;

  // sample coords span [start + 0.25*bin, start + 6.75*bin] (monotonic)
  const float ymin_s = y1s + 0.25f * bh;
  const float ymax_s = y1s + 6.75f * bh;
  const float xmin_s = x1s + 0.25f * bw;
  const float xmax_s = x1s + 6.75f * bw;
  const bool valid = (ymin_s >= -1.0f) && (ymax_s <= (float)IN_H) &&
                     (xmin_s >= -1.0f) && (xmax_s <= (float)IN_W);
  const float scale = valid ? 0.25f : 0.0f;

  // region bounding box (uniform across block)
  const float ymin_c = fminf(fmaxf(ymin_s, 0.0f), (float)(IN_H - 1));
  const float ymax_c = fminf(fmaxf(ymax_s, 0.0f), (float)(IN_H - 1));
  const float xmin_c = fminf(fmaxf(xmin_s, 0.0f), (float)(IN_W - 1));
  const float xmax_c = fminf(fmaxf(xmax_s, 0.0f), (float)(IN_W - 1));
  const int ylo = (int)floorf(ymin_c);
  const int yhi = min((int)floorf(ymax_c) + 1, IN_H - 1);
  const int xlo = (int)floorf(xmin_c);
  const int xhi = min((int)floorf(xmax_c) + 1, IN_W - 1);
  const int Hr = yhi - ylo + 1;
  const int Wr = xhi - xlo + 1;

  // ---- stage: wave `wave` stages channel c's region into sreg[wave] ----
  const float* plane = input + ((size_t)b * NCH + c) * PLANE;
  {
    const int rpi = 64 / Wr;            // rows per wave-iteration
    const int ry0 = lane / Wr;          // runtime div, once
    const int rx  = lane - ry0 * Wr;
    if (ry0 < rpi) {
      const float* src = plane + (size_t)(ylo + ry0) * IN_W + xlo + rx;
      float* dst = &sreg[wave][ry0 * Wr + rx];
      for (int ry = ry0; ry < Hr; ry += rpi) {
        *dst = *src;
        src += (size_t)rpi * IN_W;
        dst += rpi * Wr;
      }
    }
  }
  __syncthreads();

  // ---- compute: lane = output pixel, gather from LDS ----
  if (lane < OUT_HW) {
    const int ph = lane / 7;
    const int pw = lane - ph * 7;
    const float ybase = y1s + bh * (float)ph;
    const float xbase = x1s + bw * (float)pw;
    const float* reg = sreg[wave];

    float acc = 0.0f;
#pragma unroll
    for (int iy = 0; iy < 2; ++iy) {
      const float y  = ybase + (bh * 0.5f) * ((float)iy + 0.5f);
      const float yc = fminf(fmaxf(y, 0.0f), (float)(IN_H - 1));
      const float ylf = floorf(yc);
      const int   yl  = (int)ylf;
      const float ly  = yc - ylf;
      const float hy  = 1.0f - ly;
      const int ryl = yl - ylo;
      const int ryh = ryl + ((yl < IN_H - 1) ? 1 : 0);
#pragma unroll
      for (int ix = 0; ix < 2; ++ix) {
        const float x  = xbase + (bw * 0.5f) * ((float)ix + 0.5f);
        const float xc = fminf(fmaxf(x, 0.0f), (float)(IN_W - 1));
        const float xlf = floorf(xc);
        const int   xl  = (int)xlf;
        const float lx  = xc - xlf;
        const float hx  = 1.0f - lx;
        const int rxl = xl - xlo;
        const int rxh = rxl + ((xl < IN_W - 1) ? 1 : 0);

        const float v1 = reg[ryl * Wr + rxl];
        const float v2 = reg[ryl * Wr + rxh];
        const float v3 = reg[ryh * Wr + rxl];
        const float v4 = reg[ryh * Wr + rxh];

        acc += hy * hx * v1 + hy * lx * v2 + ly * hx * v3 + ly * lx * v4;
      }
    }
    const size_t oidx = ((size_t)k * NCH + c) * OUT_HW + lane;
    out[oidx] = acc * scale;
  }
}

extern "C" void kernel_launch(void* const* d_in, const int* in_sizes, int n_in,
                              void* d_out, int out_size, void* d_ws, size_t ws_size,
                              hipStream_t stream) {
  const float* input = (const float*)d_in[0];
  const float* rois  = (const float*)d_in[1];
  float* out = (float*)d_out;

  const int blocks = NROI * (NCH / 4);  // 32768
  roi_align_kernel<<<blocks, 256, 0, stream>>>(input, rois, out);
}

// Round 4
// 72.052 us; speedup vs baseline: 2.8879x; 2.8879x over previous
//
#include <hip/hip_runtime.h>

#define IN_H 200
#define IN_W 200
#define NCH  256
#define NROI 512
#define OUT_HW 49
#define PLANE (IN_H * IN_W)

// ---------------- kernel 1: NCHW f32 -> NHWC f32 transpose ----------------
// in[b][c][hw] -> nhwc[b][hw][c]; tiles of 64c x 64hw via LDS.
__global__ __launch_bounds__(256) void transpose_kernel(
    const float* __restrict__ in, float* __restrict__ nhwc) {
  __shared__ float t[64][65];
  const int blk = blockIdx.x;
  const int hwt = blk % 625;
  const int rem = blk / 625;
  const int ct  = rem & 3;
  const int b   = rem >> 2;
  const int w = threadIdx.x >> 6, l = threadIdx.x & 63;

  const float* src = in + ((size_t)b * NCH + ct * 64) * PLANE + hwt * 64;
#pragma unroll
  for (int i = 0; i < 16; ++i) {
    const int cl = w * 16 + i;
    t[cl][l] = src[(size_t)cl * PLANE + l];
  }
  __syncthreads();
  float* dst = nhwc + ((size_t)b * PLANE + hwt * 64) * NCH + ct * 64;
#pragma unroll
  for (int i = 0; i < 16; ++i) {
    const int hl = w * 16 + i;
    dst[(size_t)hl * NCH + l] = t[l][hl];
  }
}

// ---------------- kernel 2: ROIAlign from NHWC ----------------
// block = one roi; thread t: channels c0=(t&127)*2, pixels p = (t>>7) + 4*j
__global__ __launch_bounds__(512) void roi_nhwc_kernel(
    const float* __restrict__ nhwc,
    const float* __restrict__ rois,
    float* __restrict__ out) {
  __shared__ float sout[NCH * OUT_HW];  // 50176 B

  const int k  = blockIdx.x;
  const int t  = threadIdx.x;
  const int pg = t >> 7;          // 0..3
  const int c0 = (t & 127) * 2;

  const float* r = rois + k * 5;
  const int   b   = (int)r[0];
  const float x1s = r[1] * 0.25f;
  const float y1s = r[2] * 0.25f;
  const float x2s = r[3] * 0.25f;
  const float y2s = r[4] * 0.25f;
  const float roi_w = fmaxf(x2s - x1s, 1.0f);
  const float roi_h = fmaxf(y2s - y1s, 1.0f);
  const float bw = roi_w / 7.0f;
  const float bh = roi_h / 7.0f;

  // whole-roi validity (coords monotone in (p,i))
  const bool valid = (y1s + 0.25f * bh >= -1.0f) && (y1s + 6.75f * bh <= (float)IN_H) &&
                     (x1s + 0.25f * bw >= -1.0f) && (x1s + 6.75f * bw <= (float)IN_W);
  const float scale = valid ? 0.25f : 0.0f;

  const float* base = nhwc + (size_t)b * PLANE * NCH;

  for (int p = pg; p < OUT_HW; p += 4) {
    const int ph = p / 7;
    const int pw = p - ph * 7;
    const float ybase = y1s + bh * (float)ph;
    const float xbase = x1s + bw * (float)pw;

    float acc0 = 0.0f, acc1 = 0.0f;
#pragma unroll
    for (int iy = 0; iy < 2; ++iy) {
      const float y  = ybase + (bh * 0.5f) * ((float)iy + 0.5f);
      const float yc = fminf(fmaxf(y, 0.0f), (float)(IN_H - 1));
      const float ylf = floorf(yc);
      const int   yl  = (int)ylf;
      const int   yh  = min(yl + 1, IN_H - 1);
      const float ly  = yc - ylf;
      const float hy  = 1.0f - ly;
      const float* rowl = base + (size_t)yl * IN_W * NCH;
      const float* rowh = base + (size_t)yh * IN_W * NCH;
#pragma unroll
      for (int ix = 0; ix < 2; ++ix) {
        const float x  = xbase + (bw * 0.5f) * ((float)ix + 0.5f);
        const float xc = fminf(fmaxf(x, 0.0f), (float)(IN_W - 1));
        const float xlf = floorf(xc);
        const int   xl  = (int)xlf;
        const int   xh  = min(xl + 1, IN_W - 1);
        const float lx  = xc - xlf;
        const float hx  = 1.0f - lx;

        const float2 v1 = *(const float2*)(rowl + xl * NCH + c0);
        const float2 v2 = *(const float2*)(rowl + xh * NCH + c0);
        const float2 v3 = *(const float2*)(rowh + xl * NCH + c0);
        const float2 v4 = *(const float2*)(rowh + xh * NCH + c0);

        const float w1 = hy * hx, w2 = hy * lx, w3 = ly * hx, w4 = ly * lx;
        acc0 += w1 * v1.x + w2 * v2.x + w3 * v3.x + w4 * v4.x;
        acc1 += w1 * v1.y + w2 * v2.y + w3 * v3.y + w4 * v4.y;
      }
    }
    sout[c0 * OUT_HW + p]       = acc0 * scale;
    sout[(c0 + 1) * OUT_HW + p] = acc1 * scale;
  }
  __syncthreads();

  // coalesced contiguous write of the whole roi's output tile
  float4* o4 = (float4*)(out + (size_t)k * NCH * OUT_HW);
  const float4* s4 = (const float4*)sout;
#pragma unroll
  for (int m = t; m < (NCH * OUT_HW) / 4; m += 512) o4[m] = s4[m];
}

// ---------------- fallback (ws too small): round-1 direct gather ----------------
__global__ __launch_bounds__(256) void roi_align_fallback(
    const float* __restrict__ input,
    const float* __restrict__ rois,
    float* __restrict__ out) {
  const int blk  = blockIdx.x;
  const int k    = blk >> 6;
  const int cg   = blk & 63;
  const int wave = threadIdx.x >> 6;
  const int lane = threadIdx.x & 63;
  const int c    = (cg << 2) + wave;

  const float* r = rois + k * 5;
  const int   b   = (int)r[0];
  const float x1s = r[1] * 0.25f;
  const float y1s = r[2] * 0.25f;
  const float roi_w = fmaxf(r[3] * 0.25f - x1s, 1.0f);
  const float roi_h = fmaxf(r[4] * 0.25f - y1s, 1.0f);
  const float bw = roi_w / 7.0f;
  const float bh = roi_h / 7.0f;
  const bool valid = (y1s + 0.25f * bh >= -1.0f) && (y1s + 6.75f * bh <= (float)IN_H) &&
                     (x1s + 0.25f * bw >= -1.0f) && (x1s + 6.75f * bw <= (float)IN_W);
  if (lane >= OUT_HW) return;
  const int ph = lane / 7;
  const int pw = lane - ph * 7;
  const float* plane = input + ((size_t)(b * NCH + c)) * PLANE;
  const float ybase = y1s + bh * (float)ph;
  const float xbase = x1s + bw * (float)pw;
  float acc = 0.0f;
#pragma unroll
  for (int iy = 0; iy < 2; ++iy) {
    const float y  = ybase + (bh * 0.5f) * ((float)iy + 0.5f);
    const float yc = fminf(fmaxf(y, 0.0f), (float)(IN_H - 1));
    const float ylf = floorf(yc);
    const int yl = (int)ylf;
    const int yh = min(yl + 1, IN_H - 1);
    const float ly = yc - ylf, hy = 1.0f - ly;
#pragma unroll
    for (int ix = 0; ix < 2; ++ix) {
      const float x  = xbase + (bw * 0.5f) * ((float)ix + 0.5f);
      const float xc = fminf(fmaxf(x, 0.0f), (float)(IN_W - 1));
      const float xlf = floorf(xc);
      const int xl = (int)xlf;
      const int xh = min(xl + 1, IN_W - 1);
      const float lx = xc - xlf, hx = 1.0f - lx;
      const float* row_l = plane + yl * IN_W;
      const float* row_h = plane + yh * IN_W;
      acc += hy * hx * row_l[xl] + hy * lx * row_l[xh] +
             ly * hx * row_h[xl] + ly * lx * row_h[xh];
    }
  }
  out[((size_t)k * NCH + c) * OUT_HW + lane] = valid ? acc * 0.25f : 0.0f;
}

extern "C" void kernel_launch(void* const* d_in, const int* in_sizes, int n_in,
                              void* d_out, int out_size, void* d_ws, size_t ws_size,
                              hipStream_t stream) {
  const float* input = (const float*)d_in[0];
  const float* rois  = (const float*)d_in[1];
  float* out = (float*)d_out;

  const size_t need = (size_t)2 * PLANE * NCH * sizeof(float);  // 81.92 MB
  if (ws_size >= need) {
    float* nhwc = (float*)d_ws;
    transpose_kernel<<<2 * 4 * 625, 256, 0, stream>>>(input, nhwc);
    roi_nhwc_kernel<<<NROI, 512, 0, stream>>>(nhwc, rois, out);
  } else {
    roi_align_fallback<<<NROI * (NCH / 4), 256, 0, stream>>>(input, rois, out);
  }
}

// Round 5
// 47.398 us; speedup vs baseline: 4.3901x; 1.5202x over previous
//
#include <hip/hip_runtime.h>

#define IN_H 200
#define IN_W 200
#define NCH  256
#define NROI 512
#define OUT_HW 49
#define PLANE (IN_H * IN_W)

// ---------------- kernel 1: NCHW f32 -> NHWC bf16 ----------------
// tile = 64 hw px x 256 ch; LDS-transposed; RN-to-even f32->bf16.
__global__ __launch_bounds__(256) void transpose_bf16_kernel(
    const float* __restrict__ in, ushort* __restrict__ nhwc) {
  __shared__ ushort t[64][260];     // pad: row stride 520 B (8B-aligned, 2-way banks)
  const int blk = blockIdx.x;
  const int hwt = blk % 625;        // 625 tiles of 64 px (625*64 = 40000 = PLANE)
  const int b   = blk / 625;
  const int w = threadIdx.x >> 6, l = threadIdx.x & 63;
  const int hw0 = hwt * 64;

  const float* src = in + (size_t)b * NCH * PLANE + hw0;
#pragma unroll 4
  for (int i = 0; i < 64; ++i) {
    const int c = w * 64 + i;
    const float v = src[(size_t)c * PLANE + l];
    const unsigned u = __float_as_uint(v);
    const unsigned r = (u + 0x7fffu + ((u >> 16) & 1u)) >> 16;  // RN-even
    t[l][c] = (ushort)r;
  }
  __syncthreads();

  ushort* dst = nhwc + ((size_t)b * PLANE + hw0) * NCH;
#pragma unroll
  for (int m = threadIdx.x; m < 64 * 64; m += 256) {
    const int h = m >> 6;
    const int q = m & 63;
    *(ushort4*)(dst + (size_t)h * NCH + q * 4) = *(const ushort4*)&t[h][q * 4];
  }
}

// ---------------- kernel 2: ROIAlign from bf16 NHWC ----------------
// block = one roi, 512 threads; thread: 4 channels (ushort4), pixels p = pg+8j
__global__ __launch_bounds__(512) void roi_nhwc_bf16_kernel(
    const ushort* __restrict__ nhwc,
    const float* __restrict__ rois,
    float* __restrict__ out) {
  __shared__ float sout[NCH * OUT_HW];  // 50176 B

  const int k  = blockIdx.x;
  const int t  = threadIdx.x;
  const int pg = t >> 6;          // 0..7 (wave-uniform)
  const int c0 = (t & 63) * 4;

  const float* r = rois + k * 5;
  const int   b   = (int)r[0];
  const float x1s = r[1] * 0.25f;
  const float y1s = r[2] * 0.25f;
  const float x2s = r[3] * 0.25f;
  const float y2s = r[4] * 0.25f;
  const float roi_w = fmaxf(x2s - x1s, 1.0f);
  const float roi_h = fmaxf(y2s - y1s, 1.0f);
  const float bw = roi_w / 7.0f;
  const float bh = roi_h / 7.0f;

  // whole-roi validity (coords monotone in (p,i): min at p=0,i=0; max p=6,i=1)
  const bool valid = (y1s + 0.25f * bh >= -1.0f) && (y1s + 6.75f * bh <= (float)IN_H) &&
                     (x1s + 0.25f * bw >= -1.0f) && (x1s + 6.75f * bw <= (float)IN_W);
  const float scale = valid ? 0.25f : 0.0f;

  const ushort* base = nhwc + (size_t)b * PLANE * NCH;

  for (int p = pg; p < OUT_HW; p += 8) {
    const int ph = p / 7;
    const int pw = p - ph * 7;
    const float ybase = y1s + bh * (float)ph;
    const float xbase = x1s + bw * (float)pw;

    float acc0 = 0.0f, acc1 = 0.0f, acc2 = 0.0f, acc3 = 0.0f;
#pragma unroll
    for (int iy = 0; iy < 2; ++iy) {
      const float y  = ybase + (bh * 0.5f) * ((float)iy + 0.5f);
      const float yc = fminf(fmaxf(y, 0.0f), (float)(IN_H - 1));
      const float ylf = floorf(yc);
      const int   yl  = (int)ylf;
      const int   yh  = min(yl + 1, IN_H - 1);
      const float ly  = yc - ylf;
      const float hy  = 1.0f - ly;
      const ushort* rowl = base + (size_t)yl * IN_W * NCH + c0;
      const ushort* rowh = base + (size_t)yh * IN_W * NCH + c0;
#pragma unroll
      for (int ix = 0; ix < 2; ++ix) {
        const float x  = xbase + (bw * 0.5f) * ((float)ix + 0.5f);
        const float xc = fminf(fmaxf(x, 0.0f), (float)(IN_W - 1));
        const float xlf = floorf(xc);
        const int   xl  = (int)xlf;
        const int   xh  = min(xl + 1, IN_W - 1);
        const float lx  = xc - xlf;
        const float hx  = 1.0f - lx;

        const ushort4 u1 = *(const ushort4*)(rowl + (size_t)xl * NCH);
        const ushort4 u2 = *(const ushort4*)(rowl + (size_t)xh * NCH);
        const ushort4 u3 = *(const ushort4*)(rowh + (size_t)xl * NCH);
        const ushort4 u4 = *(const ushort4*)(rowh + (size_t)xh * NCH);

        const float w1 = hy * hx, w2 = hy * lx, w3 = ly * hx, w4 = ly * lx;
#define BF(us) __uint_as_float(((unsigned)(us)) << 16)
        acc0 += w1 * BF(u1.x) + w2 * BF(u2.x) + w3 * BF(u3.x) + w4 * BF(u4.x);
        acc1 += w1 * BF(u1.y) + w2 * BF(u2.y) + w3 * BF(u3.y) + w4 * BF(u4.y);
        acc2 += w1 * BF(u1.z) + w2 * BF(u2.z) + w3 * BF(u3.z) + w4 * BF(u4.z);
        acc3 += w1 * BF(u1.w) + w2 * BF(u2.w) + w3 * BF(u3.w) + w4 * BF(u4.w);
#undef BF
      }
    }
    sout[(c0 + 0) * OUT_HW + p] = acc0 * scale;
    sout[(c0 + 1) * OUT_HW + p] = acc1 * scale;
    sout[(c0 + 2) * OUT_HW + p] = acc2 * scale;
    sout[(c0 + 3) * OUT_HW + p] = acc3 * scale;
  }
  __syncthreads();

  // contiguous coalesced write of the roi's (C,7,7) tile
  float4* o4 = (float4*)(out + (size_t)k * NCH * OUT_HW);
  const float4* s4 = (const float4*)sout;
  for (int m = t; m < (NCH * OUT_HW) / 4; m += 512) o4[m] = s4[m];
}

// ---------------- fallback (ws too small): direct gather, f32 NCHW ----------------
__global__ __launch_bounds__(256) void roi_align_fallback(
    const float* __restrict__ input,
    const float* __restrict__ rois,
    float* __restrict__ out) {
  const int blk  = blockIdx.x;
  const int k    = blk >> 6;
  const int cg   = blk & 63;
  const int wave = threadIdx.x >> 6;
  const int lane = threadIdx.x & 63;
  const int c    = (cg << 2) + wave;

  const float* r = rois + k * 5;
  const int   b   = (int)r[0];
  const float x1s = r[1] * 0.25f;
  const float y1s = r[2] * 0.25f;
  const float roi_w = fmaxf(r[3] * 0.25f - x1s, 1.0f);
  const float roi_h = fmaxf(r[4] * 0.25f - y1s, 1.0f);
  const float bw = roi_w / 7.0f;
  const float bh = roi_h / 7.0f;
  const bool valid = (y1s + 0.25f * bh >= -1.0f) && (y1s + 6.75f * bh <= (float)IN_H) &&
                     (x1s + 0.25f * bw >= -1.0f) && (x1s + 6.75f * bw <= (float)IN_W);
  if (lane >= OUT_HW) return;
  const int ph = lane / 7;
  const int pw = lane - ph * 7;
  const float* plane = input + ((size_t)(b * NCH + c)) * PLANE;
  const float ybase = y1s + bh * (float)ph;
  const float xbase = x1s + bw * (float)pw;
  float acc = 0.0f;
#pragma unroll
  for (int iy = 0; iy < 2; ++iy) {
    const float y  = ybase + (bh * 0.5f) * ((float)iy + 0.5f);
    const float yc = fminf(fmaxf(y, 0.0f), (float)(IN_H - 1));
    const float ylf = floorf(yc);
    const int yl = (int)ylf;
    const int yh = min(yl + 1, IN_H - 1);
    const float ly = yc - ylf, hy = 1.0f - ly;
#pragma unroll
    for (int ix = 0; ix < 2; ++ix) {
      const float x  = xbase + (bw * 0.5f) * ((float)ix + 0.5f);
      const float xc = fminf(fmaxf(x, 0.0f), (float)(IN_W - 1));
      const float xlf = floorf(xc);
      const int xl = (int)xlf;
      const int xh = min(xl + 1, IN_W - 1);
      const float lx = xc - xlf, hx = 1.0f - lx;
      const float* row_l = plane + yl * IN_W;
      const float* row_h = plane + yh * IN_W;
      acc += hy * hx * row_l[xl] + hy * lx * row_l[xh] +
             ly * hx * row_h[xl] + ly * lx * row_h[xh];
    }
  }
  out[((size_t)k * NCH + c) * OUT_HW + lane] = valid ? acc * 0.25f : 0.0f;
}

extern "C" void kernel_launch(void* const* d_in, const int* in_sizes, int n_in,
                              void* d_out, int out_size, void* d_ws, size_t ws_size,
                              hipStream_t stream) {
  const float* input = (const float*)d_in[0];
  const float* rois  = (const float*)d_in[1];
  float* out = (float*)d_out;

  const size_t need = (size_t)2 * PLANE * NCH * sizeof(ushort);  // 40.96 MB
  if (ws_size >= need) {
    ushort* nhwc = (ushort*)d_ws;
    transpose_bf16_kernel<<<2 * 625, 256, 0, stream>>>(input, nhwc);
    roi_nhwc_bf16_kernel<<<NROI, 512, 0, stream>>>(nhwc, rois, out);
  } else {
    roi_align_fallback<<<NROI * (NCH / 4), 256, 0, stream>>>(input, rois, out);
  }
}